// Round 1
// baseline (9560.938 us; speedup 1.0000x reference)
//
#include <hip/hip_runtime.h>

// Problem constants
#define BATCH 256
#define TT    64
#define HH    256
#define DIN   2
#define DD    8

// Tiling
#define BW    4                      // batch rows per workgroup
#define NTHR  256
#define NBLK  (2 * (BATCH / BW))     // 2 stacks * 64 batch-blocks = 128 WGs

__device__ __forceinline__ float sigf(float x) { return 1.0f / (1.0f + __expf(-x)); }
__device__ __forceinline__ float dot4(const float4 a, const float4 b) {
  return a.x * b.x + a.y * b.y + a.z * b.z + a.w * b.w;
}

struct __align__(16) SMEM {
  float h [2][BW][HH];        // attended hidden carry (input to GRU)
  float hn[2][BW][HH];        // fresh GRU hidden this step
  float S1[BW][3 * HH];       // gate scratch (gi or gh)
  float S2[BW][3 * HH];       // gate scratch / p-partial scratch
  float es[BW][2][HH];        // current-step attention "s" projection
  float cac[2][BW][HH];       // context vectors
  float logit[BW][TT][2][2];  // attention logits -> softmax weights
  float vw[2 * HH];           // v_W cached
  float xsh[BW][DIN];         // x for this step
};

// out[b][tid + kk*HH] = bias[...] + sum_c hin[b][c] * W[(tid+kk*HH)*HH + c]
__device__ __forceinline__ void gemm768(float out[][3 * HH], const float hin[][HH],
                                        const float* __restrict__ W,
                                        const float* __restrict__ bias, int tid) {
  float acc[3][BW];
  const float4* Wr[3];
#pragma unroll
  for (int kk = 0; kk < 3; kk++) {
    const float bv = bias[tid + kk * HH];
#pragma unroll
    for (int b = 0; b < BW; b++) acc[kk][b] = bv;
    Wr[kk] = (const float4*)(W + (size_t)(tid + kk * HH) * HH);
  }
  for (int c4 = 0; c4 < HH / 4; c4++) {
    float4 hv[BW];
#pragma unroll
    for (int b = 0; b < BW; b++) hv[b] = ((const float4*)hin[b])[c4];
#pragma unroll
    for (int kk = 0; kk < 3; kk++) {
      const float4 w = Wr[kk][c4];
#pragma unroll
      for (int b = 0; b < BW; b++) acc[kk][b] += dot4(w, hv[b]);
    }
  }
#pragma unroll
  for (int kk = 0; kk < 3; kk++)
#pragma unroll
    for (int b = 0; b < BW; b++) out[b][tid + kk * HH] = acc[kk][b];
}

__global__ __launch_bounds__(NTHR) void gru_attn_persistent(
    const float* __restrict__ received,
    const float* __restrict__ g1_Wih0, const float* __restrict__ g1_Whh0,
    const float* __restrict__ g1_bih0, const float* __restrict__ g1_bhh0,
    const float* __restrict__ g1_Wih1, const float* __restrict__ g1_Whh1,
    const float* __restrict__ g1_bih1, const float* __restrict__ g1_bhh1,
    const float* __restrict__ g2_Wih0, const float* __restrict__ g2_Whh0,
    const float* __restrict__ g2_bih0, const float* __restrict__ g2_bhh0,
    const float* __restrict__ g2_Wih1, const float* __restrict__ g2_Whh1,
    const float* __restrict__ g2_bih1, const float* __restrict__ g2_bhh1,
    const float* __restrict__ fc_W, const float* __restrict__ fc_b,
    const float* __restrict__ attn_W, const float* __restrict__ v_W,
    const float* __restrict__ out_W,
    float* __restrict__ ws_buf, float* __restrict__ ws_eh, float* __restrict__ ws_p) {
  const int tid = threadIdx.x;
  const int s   = blockIdx.x & 1;   // stack: 0 -> g1, 1 -> g2
  const int bb  = blockIdx.x >> 1;  // batch block
  const int b0  = bb * BW;

  const float* Wih0 = s ? g2_Wih0 : g1_Wih0;
  const float* Whh0 = s ? g2_Whh0 : g1_Whh0;
  const float* bih0 = s ? g2_bih0 : g1_bih0;
  const float* bhh0 = s ? g2_bhh0 : g1_bhh0;
  const float* Wih1 = s ? g2_Wih1 : g1_Wih1;
  const float* Whh1 = s ? g2_Whh1 : g1_Whh1;
  const float* bih1 = s ? g2_bih1 : g1_bih1;
  const float* bhh1 = s ? g2_bhh1 : g1_bhh1;

  float* buf = ws_buf + (size_t)s * BATCH * TT * 2 * HH;  // [B][T][2][H] hidden history
  float* ehb = ws_eh  + (size_t)s * BATCH * TT * 2 * HH;  // [B][T][2][H] eh cache
  float* pp  = ws_p   + (size_t)s * BATCH * TT;           // [B][T] out partial
  const float* outw = out_W + s * HH;

  __shared__ SMEM sm;

  for (int idx = tid; idx < 2 * BW * HH; idx += NTHR) (&sm.h[0][0][0])[idx] = 0.0f;
  sm.vw[tid]      = v_W[tid];
  sm.vw[tid + HH] = v_W[tid + HH];
  __syncthreads();

#pragma unroll 1
  for (int i = 0; i < TT; ++i) {
    // ---- phase 1: load x; S1 = gh0 = h[0] @ Whh0^T + bhh0
    if (tid < BW * DIN) {
      const int b = tid >> 1, c = tid & 1;
      sm.xsh[b][c] = received[(size_t)(b0 + b) * TT * DIN + i * DIN + c];
    }
    gemm768(sm.S1, sm.h[0], Whh0, bhh0, tid);
    __syncthreads();

    // ---- phase 2: layer-0 gates -> hn[0]
    {
      const int k = tid;
      const float wr0 = Wih0[k * DIN], wr1 = Wih0[k * DIN + 1];
      const float wz0 = Wih0[(k + HH) * DIN], wz1 = Wih0[(k + HH) * DIN + 1];
      const float wn0 = Wih0[(k + 2 * HH) * DIN], wn1 = Wih0[(k + 2 * HH) * DIN + 1];
      const float br = bih0[k], bz = bih0[k + HH], bn = bih0[k + 2 * HH];
#pragma unroll
      for (int b = 0; b < BW; b++) {
        const float x0 = sm.xsh[b][0], x1 = sm.xsh[b][1];
        const float r = sigf(x0 * wr0 + x1 * wr1 + br + sm.S1[b][k]);
        const float z = sigf(x0 * wz0 + x1 * wz1 + bz + sm.S1[b][k + HH]);
        const float n = tanhf(x0 * wn0 + x1 * wn1 + bn + r * sm.S1[b][k + 2 * HH]);
        sm.hn[0][b][k] = (1.0f - z) * n + z * sm.h[0][b][k];
      }
    }
    __syncthreads();

    // ---- phase 3: S1 = gi1 = hn0 @ Wih1^T + bih1 ; S2 = gh1 = h[1] @ Whh1^T + bhh1
    gemm768(sm.S1, sm.hn[0], Wih1, bih1, tid);
    gemm768(sm.S2, sm.h[1], Whh1, bhh1, tid);
    __syncthreads();

    // ---- phase 4: layer-1 gates -> hn[1]
    {
      const int k = tid;
#pragma unroll
      for (int b = 0; b < BW; b++) {
        const float r = sigf(sm.S1[b][k] + sm.S2[b][k]);
        const float z = sigf(sm.S1[b][k + HH] + sm.S2[b][k + HH]);
        const float n = tanhf(sm.S1[b][k + 2 * HH] + r * sm.S2[b][k + 2 * HH]);
        sm.hn[1][b][k] = (1.0f - z) * n + z * sm.h[1][b][k];
      }
    }
    __syncthreads();

    // ---- phase 5: store hidden history slot i; p-partial scratch into S2
#pragma unroll
    for (int b = 0; b < BW; b++) {
#pragma unroll
      for (int l = 0; l < 2; l++)
        buf[((size_t)(b0 + b) * TT * 2 + i * 2 + l) * HH + tid] = sm.hn[l][b][tid];
      sm.S2[b][tid] = sm.hn[1][b][tid] * outw[tid];
    }
    __syncthreads();

    // ---- phase 6: p reduce; es / eh_new projections (one attn_W row per thread)
    if (tid < BW) {
      float acc = 0.0f;
      for (int c = 0; c < HH; c++) acc += sm.S2[tid][c];
      pp[(size_t)(b0 + tid) * TT + i] = acc;
    }
    {
      const int g = tid;
      const float4* row = (const float4*)(attn_W + (size_t)g * 2 * HH);
      float as[2][BW], ah[2][BW];
#pragma unroll
      for (int l = 0; l < 2; l++)
#pragma unroll
        for (int b = 0; b < BW; b++) { as[l][b] = 0.0f; ah[l][b] = 0.0f; }
      for (int c4 = 0; c4 < HH / 4; c4++) {
        const float4 w1 = row[c4];
        const float4 w2 = row[HH / 4 + c4];
#pragma unroll
        for (int l = 0; l < 2; l++)
#pragma unroll
          for (int b = 0; b < BW; b++) {
            const float4 hv = ((const float4*)sm.hn[l][b])[c4];
            as[l][b] += dot4(w1, hv);
            ah[l][b] += dot4(w2, hv);
          }
      }
#pragma unroll
      for (int l = 0; l < 2; l++)
#pragma unroll
        for (int b = 0; b < BW; b++) {
          sm.es[b][l][g] = as[l][b];
          ehb[((size_t)(b0 + b) * TT * 2 + i * 2 + l) * HH + g] = ah[l][b];
        }
    }
    __syncthreads();

    // ---- phase 7: energy tanh + logits for all (b, j<=i, l)
    {
      const int ntask = BW * 2 * (i + 1);
      const float4* v0 = (const float4*)sm.vw;
      const float4* v1 = (const float4*)(sm.vw + HH);
      for (int task = tid; task < ntask; task += NTHR) {
        const int b = task & (BW - 1);
        const int l = (task >> 2) & 1;
        const int j = task >> 3;
        const float4* ehp = (const float4*)(ehb + ((size_t)(b0 + b) * TT * 2 + j * 2 + l) * HH);
        const float4* esp = (const float4*)sm.es[b][l];
        float l0 = 0.0f, l1 = 0.0f;
        for (int g4 = 0; g4 < HH / 4; g4++) {
          const float4 eh4 = ehp[g4], es4 = esp[g4];
          const float e0 = tanhf(es4.x + eh4.x);
          const float e1 = tanhf(es4.y + eh4.y);
          const float e2 = tanhf(es4.z + eh4.z);
          const float e3 = tanhf(es4.w + eh4.w);
          const float4 a = v0[g4], c = v1[g4];
          l0 += e0 * a.x + e1 * a.y + e2 * a.z + e3 * a.w;
          l1 += e0 * c.x + e1 * c.y + e2 * c.z + e3 * c.w;
        }
        sm.logit[b][j][l][0] = l0;
        sm.logit[b][j][l][1] = l1;
      }
    }
    __syncthreads();

    // ---- phase 8: masked softmax over (j,l) per (b,o)
    if (tid < BW * 2) {
      const int b = tid >> 1, o = tid & 1;
      float m = -1e30f;
      for (int j = 0; j <= i; j++)
        for (int l = 0; l < 2; l++) m = fmaxf(m, sm.logit[b][j][l][o]);
      float ssum = 0.0f;
      for (int j = 0; j <= i; j++)
        for (int l = 0; l < 2; l++) {
          const float e = __expf(sm.logit[b][j][l][o] - m);
          sm.logit[b][j][l][o] = e;
          ssum += e;
        }
      const float inv = 1.0f / ssum;
      for (int j = 0; j <= i; j++)
        for (int l = 0; l < 2; l++) sm.logit[b][j][l][o] *= inv;
    }
    __syncthreads();

    // ---- phase 9: context c[o][b][:] = sum_{j,l} a * buf
    {
      const int b = tid >> 6;
      const int h4 = tid & 63;
      const float4* bp = (const float4*)(buf + (size_t)(b0 + b) * TT * 2 * HH);
      float4 c0 = make_float4(0.f, 0.f, 0.f, 0.f);
      float4 c1 = make_float4(0.f, 0.f, 0.f, 0.f);
      for (int j = 0; j <= i; j++)
#pragma unroll
        for (int l = 0; l < 2; l++) {
          const float a0 = sm.logit[b][j][l][0];
          const float a1 = sm.logit[b][j][l][1];
          const float4 v = bp[(size_t)(j * 2 + l) * (HH / 4) + h4];
          c0.x += a0 * v.x; c0.y += a0 * v.y; c0.z += a0 * v.z; c0.w += a0 * v.w;
          c1.x += a1 * v.x; c1.y += a1 * v.y; c1.z += a1 * v.z; c1.w += a1 * v.w;
        }
      float* d0 = &sm.cac[0][b][h4 * 4];
      d0[0] = c0.x; d0[1] = c0.y; d0[2] = c0.z; d0[3] = c0.w;
      float* d1 = &sm.cac[1][b][h4 * 4];
      d1[0] = c1.x; d1[1] = c1.y; d1[2] = c1.z; d1[3] = c1.w;
    }
    __syncthreads();

    // ---- phase 10: h = [c, hn] @ fc_W^T + fc_b  (attended carry for next step)
    {
      const int g = tid;
      const float4* row = (const float4*)(fc_W + (size_t)g * 2 * HH);
      const float bias = fc_b[g];
      float acc[2][BW];
#pragma unroll
      for (int o = 0; o < 2; o++)
#pragma unroll
        for (int b = 0; b < BW; b++) acc[o][b] = bias;
      for (int c4 = 0; c4 < HH / 4; c4++) {
        const float4 w1 = row[c4];
        const float4 w2 = row[HH / 4 + c4];
#pragma unroll
        for (int o = 0; o < 2; o++)
#pragma unroll
          for (int b = 0; b < BW; b++) {
            const float4 cv = ((const float4*)sm.cac[o][b])[c4];
            const float4 hv = ((const float4*)sm.hn[o][b])[c4];
            acc[o][b] += dot4(w1, cv) + dot4(w2, hv);
          }
      }
#pragma unroll
      for (int o = 0; o < 2; o++)
#pragma unroll
        for (int b = 0; b < BW; b++) sm.h[o][b][g] = acc[o][b];
    }
    __syncthreads();
  }
}

__global__ __launch_bounds__(256) void final_combine(const float* __restrict__ ws_p,
                                                     const float* __restrict__ out_b,
                                                     float* __restrict__ out) {
  const int gidx = blockIdx.x * blockDim.x + threadIdx.x;  // 0 .. B*T-1
  if (gidx >= BATCH * TT) return;
  const int b = gidx >> 6;
  const int t = gidx & 63;
  const int idx = (t >= TT - DD - 1) ? (TT - 1) : (t + DD);
  const float* p1 = ws_p;
  const float* p2 = ws_p + (size_t)BATCH * TT;
  const float v = p1[(size_t)b * TT + t] + p2[(size_t)b * TT + idx] + out_b[0];
  out[gidx] = 1.0f / (1.0f + __expf(-v));
}

extern "C" void kernel_launch(void* const* d_in, const int* in_sizes, int n_in,
                              void* d_out, int out_size, void* d_ws, size_t ws_size,
                              hipStream_t stream) {
  const float* received = (const float*)d_in[0];
  const float* g1_Wih0 = (const float*)d_in[1];
  const float* g1_Whh0 = (const float*)d_in[2];
  const float* g1_bih0 = (const float*)d_in[3];
  const float* g1_bhh0 = (const float*)d_in[4];
  const float* g1_Wih1 = (const float*)d_in[5];
  const float* g1_Whh1 = (const float*)d_in[6];
  const float* g1_bih1 = (const float*)d_in[7];
  const float* g1_bhh1 = (const float*)d_in[8];
  const float* g2_Wih0 = (const float*)d_in[9];
  const float* g2_Whh0 = (const float*)d_in[10];
  const float* g2_bih0 = (const float*)d_in[11];
  const float* g2_bhh0 = (const float*)d_in[12];
  const float* g2_Wih1 = (const float*)d_in[13];
  const float* g2_Whh1 = (const float*)d_in[14];
  const float* g2_bih1 = (const float*)d_in[15];
  const float* g2_bhh1 = (const float*)d_in[16];
  const float* fc_W   = (const float*)d_in[17];
  const float* fc_b   = (const float*)d_in[18];
  const float* attn_W = (const float*)d_in[19];
  const float* v_W    = (const float*)d_in[20];
  const float* out_W  = (const float*)d_in[21];
  const float* out_b  = (const float*)d_in[22];

  // Workspace layout (floats):
  //   buf (2 stacks)  : 2 * B*T*2*H = 16,777,216
  //   ehb (2 stacks)  : 16,777,216
  //   p   (2 stacks)  : 2 * B*T = 32,768
  // total ~134.4 MB
  float* ws = (float*)d_ws;
  const size_t BUFSZ = (size_t)BATCH * TT * 2 * HH;  // per-stack
  float* ws_buf = ws;
  float* ws_eh  = ws + 2 * BUFSZ;
  float* ws_p   = ws + 4 * BUFSZ;

  hipLaunchKernelGGL(gru_attn_persistent, dim3(NBLK), dim3(NTHR), 0, stream,
                     received,
                     g1_Wih0, g1_Whh0, g1_bih0, g1_bhh0, g1_Wih1, g1_Whh1, g1_bih1, g1_bhh1,
                     g2_Wih0, g2_Whh0, g2_bih0, g2_bhh0, g2_Wih1, g2_Whh1, g2_bih1, g2_bhh1,
                     fc_W, fc_b, attn_W, v_W, out_W,
                     ws_buf, ws_eh, ws_p);

  hipLaunchKernelGGL(final_combine, dim3((BATCH * TT + 255) / 256), dim3(256), 0, stream,
                     ws_p, out_b, (float*)d_out);
}

// Round 2
// 7806.341 us; speedup vs baseline: 1.2248x; 1.2248x over previous
//
#include <hip/hip_runtime.h>

// Problem constants
#define BATCH 256
#define TT    64
#define HH    256
#define DIN   2
#define DD    8

// Tiling: 2 stacks * 128 batch-blocks of BW=2 -> 256 WGs (1 per CU), 512 thr (8 waves)
#define BW    2
#define NTHR  512
#define NBLK  (2 * (BATCH / BW))

__device__ __forceinline__ float rcpf(float x) { return __builtin_amdgcn_rcpf(x); }
__device__ __forceinline__ float sigf(float x) { return rcpf(1.0f + __expf(-x)); }
__device__ __forceinline__ float tanh_fast(float x) {
  const float ax = fabsf(x);
  const float t  = __expf(-2.0f * ax);
  const float r  = (1.0f - t) * rcpf(1.0f + t);
  return copysignf(r, x);
}
__device__ __forceinline__ float dot4(const float4 a, const float4 b) {
  return a.x * b.x + a.y * b.y + a.z * b.z + a.w * b.w;
}

struct __align__(16) SMEM {
  float h [2][BW][HH];           // attended carry (layer, batch, h)
  float hn[2][BW][HH];           // fresh GRU hidden
  float S1p[2][BW][3 * HH];      // gemm partials (half, b, 768)
  float S2p[2][BW][3 * HH];
  float hp[2][2][BW][HH];        // fc partials (half, o, b, g)
  float es[BW][2][264];          // s-projection, padded row (+8) for banks
  float cac[2][BW][HH];          // context (o, b, h)
  float lp[BW][TT][2][2][2];     // energy-logit partials (b, j, l, half, o)
  float aw[BW][TT][2][2];        // softmax weights (b, j, l, o)
  float vw[2 * HH];              // v_W
  float pw[8];                   // per-wave out_W partials
  float xsh[BW][DIN];
};

// Half-c GEMM: out[half][b][k + g*256] = (half==0 ? bias : 0) + sum_{c in half's 128} in[b][c]*W[k+g*256][c]
__device__ __forceinline__ void gemm_half(float out[][BW][3 * HH], const float in[][HH],
                                          const float* __restrict__ W,
                                          const float* __restrict__ bias,
                                          const int k, const int half) {
  float acc[3][BW];
  const float4* Wr[3];
#pragma unroll
  for (int g = 0; g < 3; g++) {
    const float bv = half ? 0.0f : bias[k + g * HH];
#pragma unroll
    for (int b = 0; b < BW; b++) acc[g][b] = bv;
    Wr[g] = (const float4*)(W + (size_t)(k + g * HH) * HH + half * (HH / 2));
  }
  const int cbase = half * (HH / 8);  // float4 base index into in[]
#pragma unroll 8
  for (int c4 = 0; c4 < HH / 8; c4++) {
    float4 hv[BW];
#pragma unroll
    for (int b = 0; b < BW; b++) hv[b] = ((const float4*)in[b])[cbase + c4];
#pragma unroll
    for (int g = 0; g < 3; g++) {
      const float4 w = Wr[g][c4];
#pragma unroll
      for (int b = 0; b < BW; b++) acc[g][b] += dot4(w, hv[b]);
    }
  }
#pragma unroll
  for (int g = 0; g < 3; g++)
#pragma unroll
    for (int b = 0; b < BW; b++) out[half][b][k + g * HH] = acc[g][b];
}

__global__ __launch_bounds__(NTHR, 2) void gru_attn_persistent(
    const float* __restrict__ received,
    const float* __restrict__ g1_Wih0, const float* __restrict__ g1_Whh0,
    const float* __restrict__ g1_bih0, const float* __restrict__ g1_bhh0,
    const float* __restrict__ g1_Wih1, const float* __restrict__ g1_Whh1,
    const float* __restrict__ g1_bih1, const float* __restrict__ g1_bhh1,
    const float* __restrict__ g2_Wih0, const float* __restrict__ g2_Whh0,
    const float* __restrict__ g2_bih0, const float* __restrict__ g2_bhh0,
    const float* __restrict__ g2_Wih1, const float* __restrict__ g2_Whh1,
    const float* __restrict__ g2_bih1, const float* __restrict__ g2_bhh1,
    const float* __restrict__ fc_W, const float* __restrict__ fc_b,
    const float* __restrict__ attn_W, const float* __restrict__ v_W,
    const float* __restrict__ out_W,
    float* __restrict__ ws_buf, float* __restrict__ ws_eh, float* __restrict__ ws_p) {
  const int tid = threadIdx.x;
  const int s   = blockIdx.x & 1;   // stack parity -> XCD parity (L2 weight locality)
  const int bb  = blockIdx.x >> 1;
  const int b0  = bb * BW;

  const float* Wih0 = s ? g2_Wih0 : g1_Wih0;
  const float* Whh0 = s ? g2_Whh0 : g1_Whh0;
  const float* bih0 = s ? g2_bih0 : g1_bih0;
  const float* bhh0 = s ? g2_bhh0 : g1_bhh0;
  const float* Wih1 = s ? g2_Wih1 : g1_Wih1;
  const float* Whh1 = s ? g2_Whh1 : g1_Whh1;
  const float* bih1 = s ? g2_bih1 : g1_bih1;
  const float* bhh1 = s ? g2_bhh1 : g1_bhh1;

  float* buf = ws_buf + (size_t)s * BATCH * TT * 2 * HH;
  float* ehb = ws_eh  + (size_t)s * BATCH * TT * 2 * HH;
  float* pp  = ws_p   + (size_t)s * BATCH * TT;
  const float* outw = out_W + s * HH;

  __shared__ SMEM sm;

  for (int idx = tid; idx < 2 * BW * HH; idx += NTHR) (&sm.h[0][0][0])[idx] = 0.0f;
  sm.vw[tid] = v_W[tid];
  __syncthreads();

  const int k    = tid & (HH - 1);  // 0..255
  const int half = tid >> 8;        // 0/1

#pragma unroll 1
  for (int i = 0; i < TT; ++i) {
    // ---- ph1: load x; gh0 partials into S1p
    if (tid < BW * DIN) {
      const int b = tid >> 1, c = tid & 1;
      sm.xsh[b][c] = received[(size_t)(b0 + b) * TT * DIN + i * DIN + c];
    }
    gemm_half(sm.S1p, sm.h[0], Whh0, bhh0, k, half);
    __syncthreads();

    // ---- ph2: layer-0 gates -> hn[0]   (thread = (k, b))
    {
      const int b = half;
      const float x0 = sm.xsh[b][0], x1 = sm.xsh[b][1];
      const float gr = sm.S1p[0][b][k] + sm.S1p[1][b][k];
      const float gz = sm.S1p[0][b][k + HH] + sm.S1p[1][b][k + HH];
      const float gn = sm.S1p[0][b][k + 2 * HH] + sm.S1p[1][b][k + 2 * HH];
      const float r = sigf(x0 * Wih0[k * DIN] + x1 * Wih0[k * DIN + 1] + bih0[k] + gr);
      const float z = sigf(x0 * Wih0[(k + HH) * DIN] + x1 * Wih0[(k + HH) * DIN + 1] + bih0[k + HH] + gz);
      const float n = tanh_fast(x0 * Wih0[(k + 2 * HH) * DIN] + x1 * Wih0[(k + 2 * HH) * DIN + 1] +
                                bih0[k + 2 * HH] + r * gn);
      sm.hn[0][b][k] = (1.0f - z) * n + z * sm.h[0][b][k];
    }
    __syncthreads();

    // ---- ph3: gi1 partials (from hn0) and gh1 partials (from h1)
    gemm_half(sm.S1p, sm.hn[0], Wih1, bih1, k, half);
    gemm_half(sm.S2p, sm.h[1], Whh1, bhh1, k, half);
    __syncthreads();

    // ---- ph4: layer-1 gates -> hn[1]; store buf slot i; out_W wave-partial
    {
      const int b = half;
      const float r = sigf(sm.S1p[0][b][k] + sm.S1p[1][b][k] + sm.S2p[0][b][k] + sm.S2p[1][b][k]);
      const float z = sigf(sm.S1p[0][b][k + HH] + sm.S1p[1][b][k + HH] +
                           sm.S2p[0][b][k + HH] + sm.S2p[1][b][k + HH]);
      const float n = tanh_fast(sm.S1p[0][b][k + 2 * HH] + sm.S1p[1][b][k + 2 * HH] +
                                r * (sm.S2p[0][b][k + 2 * HH] + sm.S2p[1][b][k + 2 * HH]));
      const float hn1 = (1.0f - z) * n + z * sm.h[1][b][k];
      sm.hn[1][b][k] = hn1;
      const float hn0 = sm.hn[0][b][k];
      buf[((size_t)(b0 + b) * TT * 2 + i * 2 + 0) * HH + k] = hn0;
      buf[((size_t)(b0 + b) * TT * 2 + i * 2 + 1) * HH + k] = hn1;
      float pv = hn1 * outw[k];
#pragma unroll
      for (int d = 1; d < 64; d <<= 1) pv += __shfl_xor(pv, d, 64);
      if ((tid & 63) == 0) sm.pw[tid >> 6] = pv;
    }
    __syncthreads();

    // ---- ph6: es / eh projections (thread = (g, l)); p finalize
    {
      const int g = k, l = half;
      const float4* wrow = (const float4*)(attn_W + (size_t)g * 2 * HH);
      float as[BW], ah[BW];
#pragma unroll
      for (int b = 0; b < BW; b++) { as[b] = 0.0f; ah[b] = 0.0f; }
#pragma unroll 8
      for (int c4 = 0; c4 < HH / 4; c4++) {
        const float4 w1 = wrow[c4];
        const float4 w2 = wrow[HH / 4 + c4];
#pragma unroll
        for (int b = 0; b < BW; b++) {
          const float4 hv = ((const float4*)sm.hn[l][b])[c4];
          as[b] += dot4(w1, hv);
          ah[b] += dot4(w2, hv);
        }
      }
#pragma unroll
      for (int b = 0; b < BW; b++) {
        sm.es[b][l][g] = as[b];
        ehb[((size_t)(b0 + b) * TT * 2 + i * 2 + l) * HH + g] = ah[b];
      }
      if (tid < BW)
        pp[(size_t)(b0 + tid) * TT + i] = sm.pw[4 * tid] + sm.pw[4 * tid + 1] +
                                          sm.pw[4 * tid + 2] + sm.pw[4 * tid + 3];
    }
    __syncthreads();

    // ---- ph7: energy tanh + logit partials, c-split  (task = (j,l,b,half))
    {
      const int ntask = 8 * (i + 1);
      for (int task = tid; task < ntask; task += NTHR) {
        const int th = task & 1;
        const int b  = (task >> 1) & 1;
        const int l  = (task >> 2) & 1;
        const int j  = task >> 3;
        const float4* ehp = (const float4*)(ehb + ((size_t)(b0 + b) * TT * 2 + j * 2 + l) * HH + th * 128);
        const float4* esp = (const float4*)(&sm.es[b][l][th * 128]);
        const float4* v0  = (const float4*)(sm.vw + th * 128);
        const float4* v1  = (const float4*)(sm.vw + HH + th * 128);
        float l0 = 0.0f, l1 = 0.0f;
#pragma unroll 8
        for (int c4 = 0; c4 < 32; c4++) {
          const float4 eh4 = ehp[c4], es4 = esp[c4];
          float4 e;
          e.x = tanh_fast(es4.x + eh4.x);
          e.y = tanh_fast(es4.y + eh4.y);
          e.z = tanh_fast(es4.z + eh4.z);
          e.w = tanh_fast(es4.w + eh4.w);
          l0 += dot4(e, v0[c4]);
          l1 += dot4(e, v1[c4]);
        }
        sm.lp[b][j][l][th][0] = l0;
        sm.lp[b][j][l][th][1] = l1;
      }
    }
    __syncthreads();

    // ---- ph8: wave-parallel masked softmax (wave per (b,o))
    if (tid < 256) {
      const int lane = tid & 63, wid = tid >> 6;
      const int b = wid >> 1, o = wid & 1;
      const int jl2 = 2 * (i + 1);
      const int jl0 = lane, jl1 = lane + 64;
      float v0 = -1e30f, v1 = -1e30f;
      if (jl0 < jl2) v0 = sm.lp[b][jl0 >> 1][jl0 & 1][0][o] + sm.lp[b][jl0 >> 1][jl0 & 1][1][o];
      if (jl1 < jl2) v1 = sm.lp[b][jl1 >> 1][jl1 & 1][0][o] + sm.lp[b][jl1 >> 1][jl1 & 1][1][o];
      float m = fmaxf(v0, v1);
#pragma unroll
      for (int d = 1; d < 64; d <<= 1) m = fmaxf(m, __shfl_xor(m, d, 64));
      float e0 = (jl0 < jl2) ? __expf(v0 - m) : 0.0f;
      float e1 = (jl1 < jl2) ? __expf(v1 - m) : 0.0f;
      float ssum = e0 + e1;
#pragma unroll
      for (int d = 1; d < 64; d <<= 1) ssum += __shfl_xor(ssum, d, 64);
      const float inv = rcpf(ssum);
      if (jl0 < jl2) sm.aw[b][jl0 >> 1][jl0 & 1][o] = e0 * inv;
      if (jl1 < jl2) sm.aw[b][jl1 >> 1][jl1 & 1][o] = e1 * inv;
    }
    __syncthreads();

    // ---- ph9: context (thread = (h, b)); aw reads broadcast per wave
    {
      const int h = k, b = half;
      const float* bp = buf + (size_t)(b0 + b) * TT * 2 * HH + h;
      float c0 = 0.0f, c1 = 0.0f;
      for (int j = 0; j <= i; j++) {
#pragma unroll
        for (int l = 0; l < 2; l++) {
          const float v  = bp[(size_t)(j * 2 + l) * HH];
          const float a0 = sm.aw[b][j][l][0];
          const float a1 = sm.aw[b][j][l][1];
          c0 += a0 * v;
          c1 += a1 * v;
        }
      }
      sm.cac[0][b][h] = c0;
      sm.cac[1][b][h] = c1;
    }
    __syncthreads();

    // ---- ph10: fc partials (thread = (g, half)): half0 over cac, half1 over hn
    {
      const int g = k;
      const float4* frow = (const float4*)(fc_W + (size_t)g * 2 * HH + half * HH);
      float acc[2][BW];
#pragma unroll
      for (int o = 0; o < 2; o++)
#pragma unroll
        for (int b = 0; b < BW; b++) acc[o][b] = 0.0f;
#pragma unroll 8
      for (int c4 = 0; c4 < HH / 4; c4++) {
        const float4 w = frow[c4];
#pragma unroll
        for (int o = 0; o < 2; o++)
#pragma unroll
          for (int b = 0; b < BW; b++) {
            const float4 hv = half ? ((const float4*)sm.hn[o][b])[c4]
                                   : ((const float4*)sm.cac[o][b])[c4];
            acc[o][b] += dot4(w, hv);
          }
      }
#pragma unroll
      for (int o = 0; o < 2; o++)
#pragma unroll
        for (int b = 0; b < BW; b++) sm.hp[half][o][b][g] = acc[o][b];
    }
    __syncthreads();

    // ---- ph10b: fold fc halves -> new attended carry h
    for (int x = tid; x < 2 * BW * HH; x += NTHR) {
      const int g = x & (HH - 1);
      const int b = (x >> 8) & (BW - 1);
      const int o = x >> 9;
      sm.h[o][b][g] = sm.hp[0][o][b][g] + sm.hp[1][o][b][g] + fc_b[g];
    }
    __syncthreads();
  }
}

__global__ __launch_bounds__(256) void final_combine(const float* __restrict__ ws_p,
                                                     const float* __restrict__ out_b,
                                                     float* __restrict__ out) {
  const int gidx = blockIdx.x * blockDim.x + threadIdx.x;
  if (gidx >= BATCH * TT) return;
  const int b = gidx >> 6;
  const int t = gidx & 63;
  const int idx = (t >= TT - DD - 1) ? (TT - 1) : (t + DD);
  const float* p1 = ws_p;
  const float* p2 = ws_p + (size_t)BATCH * TT;
  const float v = p1[(size_t)b * TT + t] + p2[(size_t)b * TT + idx] + out_b[0];
  out[gidx] = 1.0f / (1.0f + __expf(-v));
}

extern "C" void kernel_launch(void* const* d_in, const int* in_sizes, int n_in,
                              void* d_out, int out_size, void* d_ws, size_t ws_size,
                              hipStream_t stream) {
  const float* received = (const float*)d_in[0];
  const float* g1_Wih0 = (const float*)d_in[1];
  const float* g1_Whh0 = (const float*)d_in[2];
  const float* g1_bih0 = (const float*)d_in[3];
  const float* g1_bhh0 = (const float*)d_in[4];
  const float* g1_Wih1 = (const float*)d_in[5];
  const float* g1_Whh1 = (const float*)d_in[6];
  const float* g1_bih1 = (const float*)d_in[7];
  const float* g1_bhh1 = (const float*)d_in[8];
  const float* g2_Wih0 = (const float*)d_in[9];
  const float* g2_Whh0 = (const float*)d_in[10];
  const float* g2_bih0 = (const float*)d_in[11];
  const float* g2_bhh0 = (const float*)d_in[12];
  const float* g2_Wih1 = (const float*)d_in[13];
  const float* g2_Whh1 = (const float*)d_in[14];
  const float* g2_bih1 = (const float*)d_in[15];
  const float* g2_bhh1 = (const float*)d_in[16];
  const float* fc_W   = (const float*)d_in[17];
  const float* fc_b   = (const float*)d_in[18];
  const float* attn_W = (const float*)d_in[19];
  const float* v_W    = (const float*)d_in[20];
  const float* out_W  = (const float*)d_in[21];
  const float* out_b  = (const float*)d_in[22];

  float* ws = (float*)d_ws;
  const size_t BUFSZ = (size_t)BATCH * TT * 2 * HH;
  float* ws_buf = ws;
  float* ws_eh  = ws + 2 * BUFSZ;
  float* ws_p   = ws + 4 * BUFSZ;

  hipLaunchKernelGGL(gru_attn_persistent, dim3(NBLK), dim3(NTHR), 0, stream,
                     received,
                     g1_Wih0, g1_Whh0, g1_bih0, g1_bhh0, g1_Wih1, g1_Whh1, g1_bih1, g1_bhh1,
                     g2_Wih0, g2_Whh0, g2_bih0, g2_bhh0, g2_Wih1, g2_Whh1, g2_bih1, g2_bhh1,
                     fc_W, fc_b, attn_W, v_W, out_W,
                     ws_buf, ws_eh, ws_p);

  hipLaunchKernelGGL(final_combine, dim3((BATCH * TT + 255) / 256), dim3(256), 0, stream,
                     ws_p, out_b, (float*)d_out);
}